// Round 1
// baseline (4019.640 us; speedup 1.0000x reference)
//
#include <hip/hip_runtime.h>
#include <hip/hip_bf16.h>

#define BB 16
#define NN 2048
#define DD 1024
#define PP 2048

#define QBLK 32
#define PBLK 64

typedef _Float16 half8 __attribute__((ext_vector_type(8)));
typedef float f32x4 __attribute__((ext_vector_type(4)));

// ---------------------------------------------------------------------------
// Prep: prototypes f32 [P][D] -> fp16 row-major pf16 [P][D] and fp16
// transposed pT [D][P] (for the O-phase B-operand, k=p contiguous).
// ---------------------------------------------------------------------------
__global__ __launch_bounds__(256) void prep_kernel(const float* __restrict__ proto,
                                                   _Float16* __restrict__ pf16,
                                                   _Float16* __restrict__ pT) {
  __shared__ _Float16 T[64][65];  // +1 pad: conflict-free transpose
  const int blk = blockIdx.x;
  const int p0 = (blk & 31) << 6;   // P/64 = 32 tiles
  const int d0 = (blk >> 5) << 6;   // D/64 = 16 tiles
  const int tid = threadIdx.x;
#pragma unroll
  for (int i = 0; i < 16; ++i) {
    const int idx = (i << 8) + tid;
    const int pr = idx >> 6, dc = idx & 63;
    const float v = proto[(size_t)(p0 + pr) * DD + d0 + dc];
    const _Float16 h = (_Float16)v;
    pf16[(size_t)(p0 + pr) * DD + d0 + dc] = h;
    T[pr][dc] = h;
  }
  __syncthreads();
#pragma unroll
  for (int i = 0; i < 16; ++i) {
    const int idx = (i << 8) + tid;
    const int dr = idx >> 6, pc = idx & 63;
    pT[(size_t)(d0 + dr) * PP + p0 + pc] = T[pc][dr];
  }
}

// ---------------------------------------------------------------------------
// Fused flash-style kernel.
// Block: 512 threads (8 waves), 32 q-rows. Grid: B * N/32 = 1024.
// S-phase wave roles: q-half = w&1 (16 rows), p-sub = w>>1 (16 of PBLK=64).
// O-phase wave roles: q-half = w&1, d-chunk = (w>>1)*256.
// ---------------------------------------------------------------------------
__global__ __launch_bounds__(512, 2) void attn_kernel(
    const float* __restrict__ x, const float* __restrict__ u,
    const _Float16* __restrict__ pf16, const _Float16* __restrict__ pT,
    float* __restrict__ out) {
  __shared__ _Float16 Qs[QBLK * DD];    // 64KB, row-major 2048B/row, XOR-swizzled
  __shared__ _Float16 Pr[QBLK * PBLK];  // 4KB probs, row-major 128B/row, swizzled
  __shared__ float redM[4][QBLK];       // per-p-sub tile row maxes
  __shared__ float redS[4][QBLK];       // final l merge only

  const int tid = threadIdx.x;
  const int w = tid >> 6;
  const int lane = tid & 63;
  const int l15 = lane & 15;
  const int lg = lane >> 4;

  const int bx = blockIdx.x;
  const int b = bx >> 6;             // N/QBLK = 64 q-blocks per batch
  const int n0 = (bx & 63) << 5;

  // ---- stage Q (f32 -> fp16) into swizzled LDS; coalesced 32B/thread ----
  const float* xb = x + ((size_t)b * NN + n0) * DD;
#pragma unroll
  for (int i = 0; i < 8; ++i) {
    const int idx = (i << 9) + tid;       // 4096 chunks of 8 elems
    const int q = idx >> 7;
    const int dc = (idx & 127) << 3;
    const float4 v0 = *(const float4*)(xb + (size_t)q * DD + dc);
    const float4 v1 = *(const float4*)(xb + (size_t)q * DD + dc + 4);
    half8 h;
    h[0] = (_Float16)v0.x; h[1] = (_Float16)v0.y;
    h[2] = (_Float16)v0.z; h[3] = (_Float16)v0.w;
    h[4] = (_Float16)v1.x; h[5] = (_Float16)v1.y;
    h[6] = (_Float16)v1.z; h[7] = (_Float16)v1.w;
    const int byte = (dc << 1) ^ ((q & 7) << 4);  // write-side same-row: conflict-free
    *(half8*)((char*)Qs + q * 2048 + byte) = h;
  }
  __syncthreads();

  const int qs = (w & 1) << 4;    // q-subtile base (S and O phases)
  const int ps = (w >> 1) << 4;   // p-subtile within PBLK (S phase)
  const int dch = (w >> 1) << 8;  // d-chunk base (O phase)

  const f32x4 zero4 = {0.f, 0.f, 0.f, 0.f};
  f32x4 oacc[16];
#pragma unroll
  for (int t = 0; t < 16; ++t) oacc[t] = zero4;

  const int arow = qs + l15;                       // A-frag row (S and O A share this)
  const char* aBase = (const char*)Qs + arow * 2048;
  const int ax = lg << 4;                          // k-group byte offset within row
  const int rowx = (arow & 7) << 4;                // XOR swizzle term
  const char* prBase = (const char*)Pr + arow * 128;

  const int qrow = qs + (lg << 2);                 // first of this lane's 4 q rows

  const float NEG_INF = -__builtin_inff();
  // running softmax state, registers, redundantly consistent across waves
  float m0 = NEG_INF, m1 = NEG_INF, m2 = NEG_INF, m3 = NEG_INF;
  float l0 = 0.f, l1 = 0.f, l2 = 0.f, l3 = 0.f;   // this wave's p-sub partial

  for (int p0i = 0; p0i < PP; p0i += PBLK) {
    // ---- S = Q @ proto^T for this wave's 16x16 subtile, full D ----
    f32x4 sacc = zero4;
    const _Float16* bptr = pf16 + (size_t)(p0i + ps + l15) * DD + (lg << 3);
#pragma unroll 4
    for (int kk = 0; kk < 32; ++kk) {
      const half8 af = *(const half8*)(aBase + ((((kk << 6) | ax) ^ rowx)));
      const half8 bf = *(const half8*)(bptr + (kk << 5));
      sacc = __builtin_amdgcn_mfma_f32_16x16x32_f16(af, bf, sacc, 0, 0, 0);
    }

    // ---- Gumbel noise: g = -log(-log(u)), u[b][p][n], exact-once stream ----
    const float4 uv = *(const float4*)(u + (size_t)b * PP * NN +
                                       (size_t)(p0i + ps + l15) * NN + n0 + qrow);
    sacc[0] -= __logf(-__logf(uv.x));
    sacc[1] -= __logf(-__logf(uv.y));
    sacc[2] -= __logf(-__logf(uv.z));
    sacc[3] -= __logf(-__logf(uv.w));

    // ---- tile row-max over this wave's 16 p (cross-lane within 16-group) ----
    float t0 = sacc[0], t1 = sacc[1], t2 = sacc[2], t3 = sacc[3];
#pragma unroll
    for (int off = 1; off < 16; off <<= 1) {
      t0 = fmaxf(t0, __shfl_xor(t0, off));
      t1 = fmaxf(t1, __shfl_xor(t1, off));
      t2 = fmaxf(t2, __shfl_xor(t2, off));
      t3 = fmaxf(t3, __shfl_xor(t3, off));
    }
    if (l15 == 0) {
      redM[w >> 1][qrow + 0] = t0;
      redM[w >> 1][qrow + 1] = t1;
      redM[w >> 1][qrow + 2] = t2;
      redM[w >> 1][qrow + 3] = t3;
    }
    __syncthreads();  // barrier A: redM ready; Pr free (prev readers done)

    // ---- merge max across 4 p-subs; update running m; rescale factor ----
    const float g0 = fmaxf(fmaxf(redM[0][qrow + 0], redM[1][qrow + 0]),
                           fmaxf(redM[2][qrow + 0], redM[3][qrow + 0]));
    const float g1 = fmaxf(fmaxf(redM[0][qrow + 1], redM[1][qrow + 1]),
                           fmaxf(redM[2][qrow + 1], redM[3][qrow + 1]));
    const float g2 = fmaxf(fmaxf(redM[0][qrow + 2], redM[1][qrow + 2]),
                           fmaxf(redM[2][qrow + 2], redM[3][qrow + 2]));
    const float g3 = fmaxf(fmaxf(redM[0][qrow + 3], redM[1][qrow + 3]),
                           fmaxf(redM[2][qrow + 3], redM[3][qrow + 3]));
    const float mn0 = fmaxf(m0, g0), mn1 = fmaxf(m1, g1);
    const float mn2 = fmaxf(m2, g2), mn3 = fmaxf(m3, g3);
    const float f0 = __expf(m0 - mn0), f1 = __expf(m1 - mn1);
    const float f2 = __expf(m2 - mn2), f3 = __expf(m3 - mn3);
    m0 = mn0; m1 = mn1; m2 = mn2; m3 = mn3;

    // ---- probs + this-wave tile row-sums; update running l ----
    const float pr0 = __expf(sacc[0] - mn0);
    const float pr1 = __expf(sacc[1] - mn1);
    const float pr2 = __expf(sacc[2] - mn2);
    const float pr3 = __expf(sacc[3] - mn3);
    float s0 = pr0, s1 = pr1, s2 = pr2, s3 = pr3;
#pragma unroll
    for (int off = 1; off < 16; off <<= 1) {
      s0 += __shfl_xor(s0, off);
      s1 += __shfl_xor(s1, off);
      s2 += __shfl_xor(s2, off);
      s3 += __shfl_xor(s3, off);
    }
    l0 = l0 * f0 + s0; l1 = l1 * f1 + s1;
    l2 = l2 * f2 + s2; l3 = l3 * f3 + s3;

    // ---- probs -> Pr (fp16, swizzled): row = q, col = ps + l15 ----
    {
      const int colb = (ps + l15) << 1;
      *(_Float16*)((char*)Pr + (qrow + 0) * 128 + (colb ^ (((qrow + 0) & 7) << 4))) = (_Float16)pr0;
      *(_Float16*)((char*)Pr + (qrow + 1) * 128 + (colb ^ (((qrow + 1) & 7) << 4))) = (_Float16)pr1;
      *(_Float16*)((char*)Pr + (qrow + 2) * 128 + (colb ^ (((qrow + 2) & 7) << 4))) = (_Float16)pr2;
      *(_Float16*)((char*)Pr + (qrow + 3) * 128 + (colb ^ (((qrow + 3) & 7) << 4))) = (_Float16)pr3;
    }

    // ---- rescale O by exp(m_old - m_new) ----
#pragma unroll
    for (int t = 0; t < 16; ++t) {
      oacc[t][0] *= f0; oacc[t][1] *= f1;
      oacc[t][2] *= f2; oacc[t][3] *= f3;
    }
    __syncthreads();  // barrier B: Pr ready for all waves

    // ---- O += probs @ proto  (A from Pr LDS, B from pT global) ----
    const half8 pa0 = *(const half8*)(prBase + ((ax) ^ rowx));
    const half8 pa1 = *(const half8*)(prBase + ((64 | ax) ^ rowx));
    const _Float16* vptr = pT + (size_t)(dch + l15) * PP + p0i + (lg << 3);
#pragma unroll 4
    for (int t = 0; t < 16; ++t) {
      const half8 vb0 = *(const half8*)(vptr + (size_t)t * 16 * PP);
      const half8 vb1 = *(const half8*)(vptr + (size_t)t * 16 * PP + 32);
      oacc[t] = __builtin_amdgcn_mfma_f32_16x16x32_f16(pa0, vb0, oacc[t], 0, 0, 0);
      oacc[t] = __builtin_amdgcn_mfma_f32_16x16x32_f16(pa1, vb1, oacc[t], 0, 0, 0);
    }
  }

  // ---- merge per-p-sub l partials, normalize, store ----
  __syncthreads();
  if (l15 == 0) {
    redS[w >> 1][qrow + 0] = l0;
    redS[w >> 1][qrow + 1] = l1;
    redS[w >> 1][qrow + 2] = l2;
    redS[w >> 1][qrow + 3] = l3;
  }
  __syncthreads();
  const float inv0 = 1.f / (redS[0][qrow + 0] + redS[1][qrow + 0] +
                            redS[2][qrow + 0] + redS[3][qrow + 0]);
  const float inv1 = 1.f / (redS[0][qrow + 1] + redS[1][qrow + 1] +
                            redS[2][qrow + 1] + redS[3][qrow + 1]);
  const float inv2 = 1.f / (redS[0][qrow + 2] + redS[1][qrow + 2] +
                            redS[2][qrow + 2] + redS[3][qrow + 2]);
  const float inv3 = 1.f / (redS[0][qrow + 3] + redS[1][qrow + 3] +
                            redS[2][qrow + 3] + redS[3][qrow + 3]);

  float* ob = out + ((size_t)b * NN + n0) * DD;
#pragma unroll
  for (int t = 0; t < 16; ++t) {
    const int d = dch + (t << 4) + l15;
    ob[(size_t)(qrow + 0) * DD + d] = oacc[t][0] * inv0;
    ob[(size_t)(qrow + 1) * DD + d] = oacc[t][1] * inv1;
    ob[(size_t)(qrow + 2) * DD + d] = oacc[t][2] * inv2;
    ob[(size_t)(qrow + 3) * DD + d] = oacc[t][3] * inv3;
  }
}

extern "C" void kernel_launch(void* const* d_in, const int* in_sizes, int n_in,
                              void* d_out, int out_size, void* d_ws, size_t ws_size,
                              hipStream_t stream) {
  const float* x = (const float*)d_in[0];
  const float* u = (const float*)d_in[1];
  const float* proto = (const float*)d_in[2];
  float* out = (float*)d_out;

  _Float16* pf16 = (_Float16*)d_ws;                   // P*D fp16
  _Float16* pT = pf16 + (size_t)PP * DD;              // D*P fp16

  hipLaunchKernelGGL(prep_kernel, dim3((PP / 64) * (DD / 64)), dim3(256), 0, stream,
                     proto, pf16, pT);
  hipLaunchKernelGGL(attn_kernel, dim3(BB * (NN / QBLK)), dim3(512), 0, stream,
                     x, u, pf16, pT, out);
}

// Round 2
// 2261.875 us; speedup vs baseline: 1.7771x; 1.7771x over previous
//
#include <hip/hip_runtime.h>
#include <hip/hip_bf16.h>

#define BB 16
#define NN 2048
#define DD 1024
#define PP 2048

#define QBLK 32
#define PBLK 64

typedef _Float16 half8 __attribute__((ext_vector_type(8)));
typedef float f32x4 __attribute__((ext_vector_type(4)));

// ---------------------------------------------------------------------------
// Prep: prototypes f32 [P][D] -> fp16 row-major pf16 [P][D] and fp16
// transposed pT [D][P] (for the O-phase B-operand, k=p contiguous).
// ---------------------------------------------------------------------------
__global__ __launch_bounds__(256) void prep_kernel(const float* __restrict__ proto,
                                                   _Float16* __restrict__ pf16,
                                                   _Float16* __restrict__ pT) {
  __shared__ _Float16 T[64][65];  // +1 pad: conflict-free transpose
  const int blk = blockIdx.x;
  const int p0 = (blk & 31) << 6;   // P/64 = 32 tiles
  const int d0 = (blk >> 5) << 6;   // D/64 = 16 tiles
  const int tid = threadIdx.x;
#pragma unroll
  for (int i = 0; i < 16; ++i) {
    const int idx = (i << 8) + tid;
    const int pr = idx >> 6, dc = idx & 63;
    const float v = proto[(size_t)(p0 + pr) * DD + d0 + dc];
    const _Float16 h = (_Float16)v;
    pf16[(size_t)(p0 + pr) * DD + d0 + dc] = h;
    T[pr][dc] = h;
  }
  __syncthreads();
#pragma unroll
  for (int i = 0; i < 16; ++i) {
    const int idx = (i << 8) + tid;
    const int dr = idx >> 6, pc = idx & 63;
    pT[(size_t)(d0 + dr) * PP + p0 + pc] = T[pc][dr];
  }
}

// ---------------------------------------------------------------------------
// Fused flash-style kernel.
// Block: 512 threads (8 waves), 32 q-rows. Grid: B * N/32 = 1024.
// S-phase wave roles: q-half = w&1 (16 rows), p-sub = w>>1 (16 of PBLK=64).
// O-phase wave roles: q-half = w&1, d-chunk = (w>>1)*256.
// ---------------------------------------------------------------------------
__global__ __launch_bounds__(512, 2) void attn_kernel(
    const float* __restrict__ x, const float* __restrict__ u,
    const _Float16* __restrict__ pf16, const _Float16* __restrict__ pT,
    float* __restrict__ out) {
  __shared__ _Float16 Qs[QBLK * DD];    // 64KB, row-major 2048B/row, XOR-swizzled
  __shared__ _Float16 Pr[QBLK * PBLK];  // 4KB probs, row-major 128B/row, swizzled
  __shared__ float redM[4][QBLK];       // per-p-sub tile row maxes
  __shared__ float redS[4][QBLK];       // final l merge only

  const int tid = threadIdx.x;
  const int w = tid >> 6;
  const int lane = tid & 63;
  const int l15 = lane & 15;
  const int lg = lane >> 4;

  const int bx = blockIdx.x;
  const int b = bx >> 6;             // N/QBLK = 64 q-blocks per batch
  const int n0 = (bx & 63) << 5;

  // ---- stage Q (f32 -> fp16) into swizzled LDS; coalesced 32B/thread ----
  const float* xb = x + ((size_t)b * NN + n0) * DD;
#pragma unroll
  for (int i = 0; i < 8; ++i) {
    const int idx = (i << 9) + tid;       // 4096 chunks of 8 elems
    const int q = idx >> 7;
    const int dc = (idx & 127) << 3;
    const float4 v0 = *(const float4*)(xb + (size_t)q * DD + dc);
    const float4 v1 = *(const float4*)(xb + (size_t)q * DD + dc + 4);
    half8 h;
    h[0] = (_Float16)v0.x; h[1] = (_Float16)v0.y;
    h[2] = (_Float16)v0.z; h[3] = (_Float16)v0.w;
    h[4] = (_Float16)v1.x; h[5] = (_Float16)v1.y;
    h[6] = (_Float16)v1.z; h[7] = (_Float16)v1.w;
    const int byte = (dc << 1) ^ ((q & 7) << 4);  // write-side same-row: conflict-free
    *(half8*)((char*)Qs + q * 2048 + byte) = h;
  }
  __syncthreads();

  const int qs = (w & 1) << 4;    // q-subtile base (S and O phases)
  const int ps = (w >> 1) << 4;   // p-subtile within PBLK (S phase)
  const int dch = (w >> 1) << 8;  // d-chunk base (O phase)

  const f32x4 zero4 = {0.f, 0.f, 0.f, 0.f};
  f32x4 oacc[16];
#pragma unroll
  for (int t = 0; t < 16; ++t) oacc[t] = zero4;

  const int arow = qs + l15;                       // A-frag row (S and O A share this)
  const char* aBase = (const char*)Qs + arow * 2048;
  const int ax = lg << 4;                          // k-group byte offset within row
  const int rowx = (arow & 7) << 4;                // XOR swizzle term
  const char* prBase = (const char*)Pr + arow * 128;

  const int qrow = qs + (lg << 2);                 // first of this lane's 4 q rows

  const float NEG_INF = -__builtin_inff();
  // running softmax state, registers, redundantly consistent across waves
  float m0 = NEG_INF, m1 = NEG_INF, m2 = NEG_INF, m3 = NEG_INF;
  float l0 = 0.f, l1 = 0.f, l2 = 0.f, l3 = 0.f;   // this wave's p-sub partial

  for (int p0i = 0; p0i < PP; p0i += PBLK) {
    // ---- Gumbel u load issued early; consumed after the S MFMAs ----
    const float4 uv = *(const float4*)(u + (size_t)b * PP * NN +
                                       (size_t)(p0i + ps + l15) * NN + n0 + qrow);

    // ---- S = Q @ proto^T for this wave's 16x16 subtile, full D ----
    f32x4 sacc = zero4;
    const _Float16* bptr = pf16 + (size_t)(p0i + ps + l15) * DD + (lg << 3);
    __builtin_amdgcn_s_setprio(1);
#pragma unroll 8
    for (int kk = 0; kk < 32; ++kk) {
      const half8 af = *(const half8*)(aBase + ((((kk << 6) | ax) ^ rowx)));
      const half8 bf = *(const half8*)(bptr + (kk << 5));
      sacc = __builtin_amdgcn_mfma_f32_16x16x32_f16(af, bf, sacc, 0, 0, 0);
    }
    __builtin_amdgcn_s_setprio(0);

    // ---- Gumbel noise: g = -log(-log(u)) ----
    sacc[0] -= __logf(-__logf(uv.x));
    sacc[1] -= __logf(-__logf(uv.y));
    sacc[2] -= __logf(-__logf(uv.z));
    sacc[3] -= __logf(-__logf(uv.w));

    // ---- tile row-max over this wave's 16 p (cross-lane within 16-group) ----
    float t0 = sacc[0], t1 = sacc[1], t2 = sacc[2], t3 = sacc[3];
#pragma unroll
    for (int off = 1; off < 16; off <<= 1) {
      t0 = fmaxf(t0, __shfl_xor(t0, off));
      t1 = fmaxf(t1, __shfl_xor(t1, off));
      t2 = fmaxf(t2, __shfl_xor(t2, off));
      t3 = fmaxf(t3, __shfl_xor(t3, off));
    }
    if (l15 == 0) {
      redM[w >> 1][qrow + 0] = t0;
      redM[w >> 1][qrow + 1] = t1;
      redM[w >> 1][qrow + 2] = t2;
      redM[w >> 1][qrow + 3] = t3;
    }
    __syncthreads();  // barrier A: redM ready; Pr free (prev readers done)

    // ---- merge max across 4 p-subs; update running m; rescale factor ----
    const float g0 = fmaxf(fmaxf(redM[0][qrow + 0], redM[1][qrow + 0]),
                           fmaxf(redM[2][qrow + 0], redM[3][qrow + 0]));
    const float g1 = fmaxf(fmaxf(redM[0][qrow + 1], redM[1][qrow + 1]),
                           fmaxf(redM[2][qrow + 1], redM[3][qrow + 1]));
    const float g2 = fmaxf(fmaxf(redM[0][qrow + 2], redM[1][qrow + 2]),
                           fmaxf(redM[2][qrow + 2], redM[3][qrow + 2]));
    const float g3 = fmaxf(fmaxf(redM[0][qrow + 3], redM[1][qrow + 3]),
                           fmaxf(redM[2][qrow + 3], redM[3][qrow + 3]));
    const float mn0 = fmaxf(m0, g0), mn1 = fmaxf(m1, g1);
    const float mn2 = fmaxf(m2, g2), mn3 = fmaxf(m3, g3);
    const float f0 = __expf(m0 - mn0), f1 = __expf(m1 - mn1);
    const float f2 = __expf(m2 - mn2), f3 = __expf(m3 - mn3);
    m0 = mn0; m1 = mn1; m2 = mn2; m3 = mn3;

    // ---- probs + this-wave tile row-sums; update running l ----
    const float pr0 = __expf(sacc[0] - mn0);
    const float pr1 = __expf(sacc[1] - mn1);
    const float pr2 = __expf(sacc[2] - mn2);
    const float pr3 = __expf(sacc[3] - mn3);
    float s0 = pr0, s1 = pr1, s2 = pr2, s3 = pr3;
#pragma unroll
    for (int off = 1; off < 16; off <<= 1) {
      s0 += __shfl_xor(s0, off);
      s1 += __shfl_xor(s1, off);
      s2 += __shfl_xor(s2, off);
      s3 += __shfl_xor(s3, off);
    }
    l0 = l0 * f0 + s0; l1 = l1 * f1 + s1;
    l2 = l2 * f2 + s2; l3 = l3 * f3 + s3;

    // ---- probs -> Pr (fp16, swizzled): row = q, col = ps + l15 ----
    {
      const int colb = (ps + l15) << 1;
      *(_Float16*)((char*)Pr + (qrow + 0) * 128 + (colb ^ (((qrow + 0) & 7) << 4))) = (_Float16)pr0;
      *(_Float16*)((char*)Pr + (qrow + 1) * 128 + (colb ^ (((qrow + 1) & 7) << 4))) = (_Float16)pr1;
      *(_Float16*)((char*)Pr + (qrow + 2) * 128 + (colb ^ (((qrow + 2) & 7) << 4))) = (_Float16)pr2;
      *(_Float16*)((char*)Pr + (qrow + 3) * 128 + (colb ^ (((qrow + 3) & 7) << 4))) = (_Float16)pr3;
    }

    // ---- rescale O by exp(m_old - m_new); skip when all factors are 1.0
    //      (uniform vote; after max stabilizes most iterations skip) ----
    if (__any((f0 < 1.f) | (f1 < 1.f) | (f2 < 1.f) | (f3 < 1.f))) {
#pragma unroll
      for (int t = 0; t < 16; ++t) {
        oacc[t][0] *= f0; oacc[t][1] *= f1;
        oacc[t][2] *= f2; oacc[t][3] *= f3;
      }
    }
    __syncthreads();  // barrier B: Pr ready for all waves

    // ---- O += probs @ proto  (A from Pr LDS, B from pT global) ----
    // FULL unroll: oacc must stay register-resident (rule #20 — partial
    // unroll here sent the accumulator to scratch: 8.5 GB WRITE_SIZE, 3% MfmaUtil)
    const half8 pa0 = *(const half8*)(prBase + ((ax) ^ rowx));
    const half8 pa1 = *(const half8*)(prBase + ((64 | ax) ^ rowx));
    const _Float16* vptr = pT + (size_t)(dch + l15) * PP + p0i + (lg << 3);
    __builtin_amdgcn_s_setprio(1);
#pragma unroll
    for (int t = 0; t < 16; ++t) {
      const half8 vb0 = *(const half8*)(vptr + (size_t)t * 16 * PP);
      const half8 vb1 = *(const half8*)(vptr + (size_t)t * 16 * PP + 32);
      oacc[t] = __builtin_amdgcn_mfma_f32_16x16x32_f16(pa0, vb0, oacc[t], 0, 0, 0);
      oacc[t] = __builtin_amdgcn_mfma_f32_16x16x32_f16(pa1, vb1, oacc[t], 0, 0, 0);
    }
    __builtin_amdgcn_s_setprio(0);
  }

  // ---- merge per-p-sub l partials, normalize, store ----
  __syncthreads();
  if (l15 == 0) {
    redS[w >> 1][qrow + 0] = l0;
    redS[w >> 1][qrow + 1] = l1;
    redS[w >> 1][qrow + 2] = l2;
    redS[w >> 1][qrow + 3] = l3;
  }
  __syncthreads();
  const float inv0 = 1.f / (redS[0][qrow + 0] + redS[1][qrow + 0] +
                            redS[2][qrow + 0] + redS[3][qrow + 0]);
  const float inv1 = 1.f / (redS[0][qrow + 1] + redS[1][qrow + 1] +
                            redS[2][qrow + 1] + redS[3][qrow + 1]);
  const float inv2 = 1.f / (redS[0][qrow + 2] + redS[1][qrow + 2] +
                            redS[2][qrow + 2] + redS[3][qrow + 2]);
  const float inv3 = 1.f / (redS[0][qrow + 3] + redS[1][qrow + 3] +
                            redS[2][qrow + 3] + redS[3][qrow + 3]);

  float* ob = out + ((size_t)b * NN + n0) * DD;
#pragma unroll
  for (int t = 0; t < 16; ++t) {
    const int d = dch + (t << 4) + l15;
    ob[(size_t)(qrow + 0) * DD + d] = oacc[t][0] * inv0;
    ob[(size_t)(qrow + 1) * DD + d] = oacc[t][1] * inv1;
    ob[(size_t)(qrow + 2) * DD + d] = oacc[t][2] * inv2;
    ob[(size_t)(qrow + 3) * DD + d] = oacc[t][3] * inv3;
  }
}

extern "C" void kernel_launch(void* const* d_in, const int* in_sizes, int n_in,
                              void* d_out, int out_size, void* d_ws, size_t ws_size,
                              hipStream_t stream) {
  const float* x = (const float*)d_in[0];
  const float* u = (const float*)d_in[1];
  const float* proto = (const float*)d_in[2];
  float* out = (float*)d_out;

  _Float16* pf16 = (_Float16*)d_ws;                   // P*D fp16
  _Float16* pT = pf16 + (size_t)PP * DD;              // D*P fp16

  hipLaunchKernelGGL(prep_kernel, dim3((PP / 64) * (DD / 64)), dim3(256), 0, stream,
                     proto, pf16, pT);
  hipLaunchKernelGGL(attn_kernel, dim3(BB * (NN / QBLK)), dim3(512), 0, stream,
                     x, u, pf16, pT, out);
}